// Round 2
// baseline (253.870 us; speedup 1.0000x reference)
//
#include <hip/hip_runtime.h>
#include <math.h>

// Problem constants (from reference)
#define N_IMG 2
#define R_PROP 256
#define G_GT 64
#define C_CH 1024
#define FH 50
#define FW 80
#define P_POOL 14
#define NCLS 80
#define IMG_W_F 1280.0f
#define IMG_H_F 800.0f
#define SCALE_F 0.0625f
#define SCORE_TH_F 0.05f
#define NMS_TH_F 0.5f
#define IOU_TH_F 0.5f
#define MAX_DET_I 100
#define SCALE_CLAMP_F 4.135166556742356f  // log(1000/16)
#define TASK_CAP 11264                    // 512 proposals * <=21 rows, padded

// ---------------------------------------------------------------------------
// Kernel 1 (prep): y-sort, gt matching, row-task list + per-task wy weights,
// prefix offsets, queue counter reset.
// ---------------------------------------------------------------------------
__global__ __launch_bounds__(512) void prep_kernel(
    const float* __restrict__ proposals,  // (N,R,4)
    const float* __restrict__ gt_boxes,   // (N,G,4)
    int* __restrict__ off,                // (513) task prefix per sorted slot
    int* __restrict__ sblk,               // (512) sorted slot -> proposal id
    int* __restrict__ task_p,             // (TASK_CAP)
    int* __restrict__ task_y,             // (TASK_CAP)
    float* __restrict__ task_wy,          // (TASK_CAP)
    int* __restrict__ counter,            // queue counter
    float* __restrict__ out_idx,          // (N,R) as float
    float* __restrict__ out_lbl) {        // (N,R) as float
  const int t = threadIdx.x;      // 0..511  (global proposal id)
  const int n = t >> 8;
  __shared__ float cy[N_IMG * R_PROP];
  __shared__ int s_sblk[N_IMG * R_PROP];
  __shared__ int s_nr[N_IMG * R_PROP];

  const float* pb = proposals + (size_t)t * 4;
  float bx1 = pb[0], by1 = pb[1], bx2 = pb[2], by2 = pb[3];
  cy[t] = by1 + by2;              // 2*cy, monotone in cy
  if (t == 0) counter[0] = 0;
  __syncthreads();

  // y-rank within image -> sorted slot
  {
    float my = cy[t];
    int rk = 0;
    const int base = n * R_PROP;
#pragma unroll 8
    for (int j = base; j < base + R_PROP; ++j) {
      float cj = cy[j];
      rk += (cj < my) || (cj == my && j < t);
    }
    s_sblk[base + rk] = t;
  }
  __syncthreads();

  // thread t now acts as SORTED slot s=t
  const int p = s_sblk[t];
  int ylo, nr;
  float b1y, bsy;
  {
    float py1 = proposals[(size_t)p * 4 + 1];
    float py2 = proposals[(size_t)p * 4 + 3];
    b1y = py1 * SCALE_F;
    float b2y = py2 * SCALE_F;
    bsy = (b2y - b1y) * (1.0f / P_POOL);
    float g0  = fminf(fmaxf(b1y + 0.5f  * bsy - 0.5f, 0.0f), (float)(FH - 1));
    float g13 = fminf(fmaxf(b1y + 13.5f * bsy - 0.5f, 0.0f), (float)(FH - 1));
    ylo = (int)floorf(g0);
    int yhi = min((int)floorf(g13) + 1, FH - 1);
    nr = yhi - ylo + 1;
    s_nr[t] = nr;
  }
  __syncthreads();

  // exclusive prefix over sorted slots (serial per thread; 512 LDS reads max)
  int o = 0;
  for (int j = 0; j < t; ++j) o += s_nr[j];
  off[t] = o;
  if (t == N_IMG * R_PROP - 1) off[N_IMG * R_PROP] = o + nr;
  sblk[t] = p;

  // emit row tasks with precomputed wy (same arithmetic as histogram)
  for (int r = 0; r < nr; ++r) {
    int y = ylo + r;
    float wy = 0.0f;
#pragma unroll
    for (int i = 0; i < P_POOL; ++i) {
      float gg = b1y + ((float)i + 0.5f) * bsy - 0.5f;
      gg = fminf(fmaxf(gg, 0.0f), (float)(FH - 1));
      float fl = floorf(gg);
      int i0 = (int)fl;
      int i1 = min(i0 + 1, FH - 1);
      float l = gg - fl;
      wy += (i0 == y) ? (1.0f - l) : 0.0f;
      wy += (i1 == y) ? l : 0.0f;
    }
    task_p[o + r] = p;
    task_y[o + r] = y;
    task_wy[o + r] = wy;
  }

  // gt matching (original proposal index t)
  {
    float area_b = (bx2 - bx1) * (by2 - by1);
    float best = -1.0f;
    int bidx = 0;
    const float* gt = gt_boxes + (size_t)n * G_GT * 4;
#pragma unroll 4
    for (int g = 0; g < G_GT; ++g) {
      float gx1 = gt[g * 4 + 0], gy1 = gt[g * 4 + 1];
      float gx2 = gt[g * 4 + 2], gy2 = gt[g * 4 + 3];
      float area_a = (gx2 - gx1) * (gy2 - gy1);
      float ix1 = fmaxf(gx1, bx1), iy1 = fmaxf(gy1, by1);
      float ix2 = fminf(gx2, bx2), iy2 = fminf(gy2, by2);
      float iw = fmaxf(ix2 - ix1, 0.0f), ih = fmaxf(iy2 - iy1, 0.0f);
      float inter = iw * ih;
      float iou = inter / fmaxf(area_a + area_b - inter, 1e-9f);
      if (iou > best) { best = iou; bidx = g; }
    }
    out_idx[t] = (float)bidx;
    out_lbl[t] = (best >= IOU_TH_F) ? 1.0f : 0.0f;
  }
}

// ---------------------------------------------------------------------------
// Kernel 2 (roi rows): dynamic work queue over row-level tasks. 256 threads
// per block (one float4 lane per thread over 1024 channels). All 2048 blocks
// co-resident (tiny LDS, 4 waves) -> greedy balance, makespan ~= ideal + 1 task.
// Writes wy-weighted row partial (1024 floats) per task.
// ---------------------------------------------------------------------------
__global__ __launch_bounds__(256) void roi_rows_kernel(
    const float* __restrict__ features,   // (N, FH, FW, C)
    const float* __restrict__ proposals,  // (N, R, 4)
    const int* __restrict__ task_p,
    const int* __restrict__ task_y,
    const float* __restrict__ task_wy,
    const int* __restrict__ off,          // off[512] = total tasks
    int* __restrict__ counter,
    float* __restrict__ rowbuf) {         // (TASK_CAP, 1024)
  const int t = threadIdx.x;  // 0..255
  __shared__ float s_Wx[FW];
  __shared__ int s_xb[2];
  __shared__ int s_tid;
  const int total = off[N_IMG * R_PROP];

  for (;;) {
    __syncthreads();                 // protect s_Wx/s_tid reuse
    if (t < FW) s_Wx[t] = 0.0f;
    if (t == 0) s_tid = atomicAdd(counter, 1);
    __syncthreads();
    const int tid = s_tid;
    if (tid >= total) break;         // uniform

    const int p = task_p[tid];
    const int y = task_y[tid];
    const float wy = task_wy[tid];

    if (t < P_POOL) {
      const float* pb = proposals + (size_t)p * 4;
      float b1 = pb[0] * SCALE_F, b2 = pb[2] * SCALE_F;
      float bs = (b2 - b1) * (1.0f / P_POOL);
      float gg = b1 + ((float)t + 0.5f) * bs - 0.5f;
      gg = fminf(fmaxf(gg, 0.0f), (float)(FW - 1));
      float fl = floorf(gg);
      int i0 = (int)fl;
      int i1 = min(i0 + 1, FW - 1);
      float l = gg - fl;
      atomicAdd(&s_Wx[i0], 1.0f - l);
      atomicAdd(&s_Wx[i1], l);
      if (t == 0) s_xb[0] = i0;
      if (t == P_POOL - 1) s_xb[1] = i1;
    }
    __syncthreads();

    const int xlo = s_xb[0], xhi = s_xb[1];
    const float4* row = (const float4*)(features +
        (size_t)(p >> 8) * (FH * FW * C_CH) + (size_t)y * (FW * C_CH));
    float4 acc = make_float4(0.f, 0.f, 0.f, 0.f);
#pragma unroll 4
    for (int x = xlo; x <= xhi; ++x) {
      float w = wy * s_Wx[x];
      float4 f = row[x * (C_CH / 4) + t];
      acc.x += w * f.x;
      acc.y += w * f.y;
      acc.z += w * f.z;
      acc.w += w * f.w;
    }
    ((float4*)rowbuf)[(size_t)tid * (C_CH / 4) + t] = acc;
  }
}

// ---------------------------------------------------------------------------
// Kernel 3 (finalize): per proposal — deterministic y-ascending reduce of its
// row partials, GEMV heads (12-way K split), softmax + box decode epilogue.
// ---------------------------------------------------------------------------
__global__ __launch_bounds__(1024) void finalize_kernel(
    const float* __restrict__ rowbuf,
    const int* __restrict__ off,
    const int* __restrict__ sblk,
    const float* __restrict__ proposals,
    const float* __restrict__ W_cls,      // (C, 81)
    const float* __restrict__ W_box,      // (C, 4)
    const float* __restrict__ b_cls,      // (81)
    const float* __restrict__ b_box,      // (4)
    float* __restrict__ boxes_dec,        // (N*R, 4)
    float* __restrict__ scores) {         // (N*R)
  const int s = blockIdx.x;   // sorted slot
  const int t = threadIdx.x;
  const int p = sblk[s];
  const int o = off[s];
  const int nr = off[s + 1] - o;

  __shared__ __align__(16) float sf[C_CH];
  __shared__ float s_part[12][85];
  __shared__ float sl[85];
  __shared__ float s_red2[8];

  if (t < C_CH / 4) {
    const float4* rb = (const float4*)rowbuf + (size_t)o * (C_CH / 4) + t;
    float4 a = make_float4(0.f, 0.f, 0.f, 0.f);
    for (int r = 0; r < nr; ++r) {
      float4 v = rb[(size_t)r * (C_CH / 4)];
      a.x += v.x; a.y += v.y; a.z += v.z; a.w += v.w;
    }
    const float inv = 1.0f / (float)(P_POOL * P_POOL);
    ((float4*)sf)[t] =
        make_float4(a.x * inv, a.y * inv, a.z * inv, a.w * inv);
  }
  __syncthreads();

  // GEMV over K=1024, 12-way split
  {
    const int kq = t / 85;        // 0..12 (t>=1020 -> 12, inactive)
    const int j = t - kq * 85;
    if (kq < 12) {
      float acc = 0.0f;
      if (j < 81) {
        const float* __restrict__ w = W_cls + j;
#pragma unroll 8
        for (int k = kq; k < C_CH; k += 12) acc += sf[k] * w[k * 81];
      } else {
        const float* __restrict__ w = W_box + (j - 81);
#pragma unroll 8
        for (int k = kq; k < C_CH; k += 12) acc += sf[k] * w[k * 4];
      }
      s_part[kq][j] = acc;
    }
  }
  __syncthreads();

  if (t < 85) {
    float bias = (t < 81) ? b_cls[t] : b_box[t - 81];
    float acc = bias;
#pragma unroll
    for (int q = 0; q < 12; ++q) acc += s_part[q][t];
    sl[t] = acc;
  }
  __syncthreads();

  if (t < 128) {
    float xm = (t < 81) ? sl[t] : -INFINITY;        // max over all 81
    float xf = (t < NCLS) ? sl[t] : -INFINITY;      // max over fg 80
#pragma unroll
    for (int off2 = 32; off2; off2 >>= 1) {
      xm = fmaxf(xm, __shfl_down(xm, off2, 64));
      xf = fmaxf(xf, __shfl_down(xf, off2, 64));
    }
    if ((t & 63) == 0) { s_red2[t >> 6] = xm; s_red2[2 + (t >> 6)] = xf; }
  }
  __syncthreads();
  if (t < 128) {
    const float m = fmaxf(s_red2[0], s_red2[1]);
    float xs = (t < 81) ? expf(sl[t] - m) : 0.0f;
#pragma unroll
    for (int off2 = 32; off2; off2 >>= 1) xs += __shfl_down(xs, off2, 64);
    if ((t & 63) == 0) s_red2[4 + (t >> 6)] = xs;
  }
  __syncthreads();

  if (t == 0) {
    const float m = fmaxf(s_red2[0], s_red2[1]);
    float sum = s_red2[4] + s_red2[5];
    float fgm = fmaxf(s_red2[2], s_red2[3]);
    scores[p] = expf(fgm - m) / sum;

    const float* pb = proposals + (size_t)p * 4;
    float w = pb[2] - pb[0], h = pb[3] - pb[1];
    float cx = pb[0] + 0.5f * w, cyc = pb[1] + 0.5f * h;
    float dx = sl[81] * 0.1f;
    float dy = sl[82] * 0.1f;
    float dw = fminf(sl[83] * 0.2f, SCALE_CLAMP_F);
    float dh = fminf(sl[84] * 0.2f, SCALE_CLAMP_F);
    float pcx = dx * w + cx, pcy = dy * h + cyc;
    float pw = expf(dw) * w, ph = expf(dh) * h;
    float ox1 = fminf(fmaxf(pcx - 0.5f * pw, 0.0f), IMG_W_F);
    float oy1 = fminf(fmaxf(pcy - 0.5f * ph, 0.0f), IMG_H_F);
    float ox2 = fminf(fmaxf(pcx + 0.5f * pw, 0.0f), IMG_W_F);
    float oy2 = fminf(fmaxf(pcy + 0.5f * ph, 0.0f), IMG_H_F);
    float* bd = boxes_dec + (size_t)p * 4;
    bd[0] = ox1; bd[1] = oy1; bd[2] = ox2; bd[3] = oy2;
  }
}

// ---------------------------------------------------------------------------
// Kernel 4: greedy NMS + score filter + top-100 rank + det write (LDS-only
// after the initial 256 box/score loads).
// ---------------------------------------------------------------------------
__global__ __launch_bounds__(1024) void nms_kernel(
    const float* __restrict__ boxes_dec,  // (N*R, 4)
    const float* __restrict__ scores,     // (N*R)
    float* __restrict__ det) {            // (N, R, 6)
  const int n = blockIdx.x;
  const int u = threadIdx.x;
  const int i = u & 255;
  const int q = u >> 8;           // 0..3
  const int j40 = q * 16;         // float4 index start for this quarter

  __shared__ __align__(16) float ss[R_PROP];     // scores, original order
  __shared__ float4 sbs[R_PROP];                 // sorted boxes
  __shared__ int s_part[4 * R_PROP];             // partial rank counts
  __shared__ int s_rank[R_PROP];
  __shared__ __align__(16) unsigned long long s_mask[R_PROP * 4];
  __shared__ unsigned long long s_keep[4];
  __shared__ __align__(16) float sm[R_PROP];     // masked scores, orig order

  float4 myb;
  float mys;
  if (q == 0) {
    myb = ((const float4*)boxes_dec)[n * R_PROP + i];
    mys = scores[n * R_PROP + i];
    ss[i] = mys;
  }
  __syncthreads();

  // stable descending rank (ties by original index): float4 loads, 16/thread
  {
    float s = ss[i];
    int cnt = 0;
#pragma unroll
    for (int j4 = j40; j4 < j40 + 16; ++j4) {
      float4 v = ((const float4*)ss)[j4];
      int jb = j4 * 4;
      cnt += (v.x > s) || (v.x == s && jb + 0 < i);
      cnt += (v.y > s) || (v.y == s && jb + 1 < i);
      cnt += (v.z > s) || (v.z == s && jb + 2 < i);
      cnt += (v.w > s) || (v.w == s && jb + 3 < i);
    }
    s_part[q * R_PROP + i] = cnt;
  }
  __syncthreads();
  if (q == 0) {
    int rk = s_part[i] + s_part[R_PROP + i] + s_part[2 * R_PROP + i] +
             s_part[3 * R_PROP + i];
    s_rank[i] = rk;
    sbs[rk] = myb;
  }
  __syncthreads();

  // phase 1: thread (i,q) computes mask word q of sorted box i vs sorted j
  {
    float4 bi = sbs[i];
    float area_i = (bi.z - bi.x) * (bi.w - bi.y);
    unsigned long long m = 0;
    const int j0 = q * 64;
#pragma unroll 8
    for (int jj = 0; jj < 64; ++jj) {
      float4 bj = sbs[j0 + jj];
      float area_j = (bj.z - bj.x) * (bj.w - bj.y);
      float ix1 = fmaxf(bi.x, bj.x), iy1 = fmaxf(bi.y, bj.y);
      float ix2 = fminf(bi.z, bj.z), iy2 = fminf(bi.w, bj.w);
      float iw = fmaxf(ix2 - ix1, 0.0f), ih = fmaxf(iy2 - iy1, 0.0f);
      float inter = iw * ih;
      float iou = inter / fmaxf(area_i + area_j - inter, 1e-9f);
      m |= (iou > NMS_TH_F) ? (1ull << jj) : 0ull;
    }
    s_mask[i * 4 + q] = m;
  }
  __syncthreads();

  // phase 2: branchless serial greedy pass over sorted order (thread 0).
  if (u == 0) {
    unsigned long long K0 = ~0ull, K1 = ~0ull, K2 = ~0ull, K3 = ~0ull;
#pragma unroll 16
    for (int b = 1; b < 64; ++b) {
      unsigned long long m0 = s_mask[(size_t)b * 4 + 0];
      unsigned long long sup = m0 & K0 & ((1ull << b) - 1ull);
      K0 = sup ? (K0 & ~(1ull << b)) : K0;
    }
#pragma unroll 16
    for (int b = 0; b < 64; ++b) {
      const unsigned long long* mi = &s_mask[(size_t)(64 + b) * 4];
      unsigned long long m0 = mi[0], m1 = mi[1];
      unsigned long long sup = (m0 & K0) | (m1 & K1 & ((1ull << b) - 1ull));
      K1 = sup ? (K1 & ~(1ull << b)) : K1;
    }
#pragma unroll 16
    for (int b = 0; b < 64; ++b) {
      const unsigned long long* mi = &s_mask[(size_t)(128 + b) * 4];
      unsigned long long m0 = mi[0], m1 = mi[1], m2 = mi[2];
      unsigned long long sup =
          (m0 & K0) | (m1 & K1) | (m2 & K2 & ((1ull << b) - 1ull));
      K2 = sup ? (K2 & ~(1ull << b)) : K2;
    }
#pragma unroll 16
    for (int b = 0; b < 64; ++b) {
      const unsigned long long* mi = &s_mask[(size_t)(192 + b) * 4];
      unsigned long long m0 = mi[0], m1 = mi[1], m2 = mi[2], m3 = mi[3];
      unsigned long long sup = (m0 & K0) | (m1 & K1) | (m2 & K2) |
                               (m3 & K3 & ((1ull << b) - 1ull));
      K3 = sup ? (K3 & ~(1ull << b)) : K3;
    }
    s_keep[0] = K0; s_keep[1] = K1; s_keep[2] = K2; s_keep[3] = K3;
  }
  __syncthreads();

  bool kept = false;
  if (q == 0) {
    int rk = s_rank[i];
    kept = ((s_keep[rk >> 6] >> (rk & 63)) & 1ull) && (mys > SCORE_TH_F);
    sm[i] = kept ? mys : -INFINITY;
  }
  __syncthreads();

  // top-100 rank over masked scores: float4 loads, 16/thread
  {
    float mym = sm[i];
    int cnt = 0;
#pragma unroll
    for (int j4 = j40; j4 < j40 + 16; ++j4) {
      float4 v = ((const float4*)sm)[j4];
      int jb = j4 * 4;
      cnt += (v.x > mym) || (v.x == mym && jb + 0 < i);
      cnt += (v.y > mym) || (v.y == mym && jb + 1 < i);
      cnt += (v.z > mym) || (v.z == mym && jb + 2 < i);
      cnt += (v.w > mym) || (v.w == mym && jb + 3 < i);
    }
    s_part[q * R_PROP + i] = cnt;
  }
  __syncthreads();

  if (q == 0) {
    int rk2 = s_part[i] + s_part[R_PROP + i] + s_part[2 * R_PROP + i] +
              s_part[3 * R_PROP + i];
    kept = kept && (rk2 < MAX_DET_I);
    float* dr = det + ((size_t)n * R_PROP + i) * 6;
    dr[0] = myb.x; dr[1] = myb.y; dr[2] = myb.z; dr[3] = myb.w;
    dr[4] = mys;
    dr[5] = kept ? 1.0f : 0.0f;
  }
}

// ---------------------------------------------------------------------------
extern "C" void kernel_launch(void* const* d_in, const int* in_sizes, int n_in,
                              void* d_out, int out_size, void* d_ws, size_t ws_size,
                              hipStream_t stream) {
  const float* features  = (const float*)d_in[0];  // (2,50,80,1024)
  const float* proposals = (const float*)d_in[1];  // (2,256,4)
  const float* gt_boxes  = (const float*)d_in[2];  // (2,64,4)
  // d_in[3] gt_classes: unused by reference outputs
  const float* W_cls = (const float*)d_in[4];      // (1024,81)
  const float* b_cls = (const float*)d_in[5];      // (81)
  const float* W_box = (const float*)d_in[6];      // (1024,4)
  const float* b_box = (const float*)d_in[7];      // (4)

  float* out = (float*)d_out;
  // out layout: det [0,3072) | matched_idxs [3072,3584) | match_labels [3584,4096)
  float* out_det = out;
  float* out_idx = out + N_IMG * R_PROP * 6;
  float* out_lbl = out_idx + N_IMG * R_PROP;

  // workspace layout
  int*   counter = (int*)d_ws;                     // [0] queue counter
  int*   off     = counter + 16;                   // 513 ints
  int*   sblk    = off + 520;                      // 512 ints
  int*   task_p  = sblk + 512;                     // TASK_CAP ints
  int*   task_y  = task_p + TASK_CAP;              // TASK_CAP ints
  float* task_wy = (float*)(task_y + TASK_CAP);    // TASK_CAP floats
  float* rowbuf  = (float*)((char*)d_ws + 262144); // TASK_CAP * 1024 floats (~46 MB)
  float* boxes_dec =
      (float*)((char*)d_ws + 262144 + (size_t)TASK_CAP * C_CH * 4);
  float* scores = boxes_dec + N_IMG * R_PROP * 4;

  prep_kernel<<<1, 512, 0, stream>>>(proposals, gt_boxes, off, sblk, task_p,
                                     task_y, task_wy, counter, out_idx, out_lbl);
  roi_rows_kernel<<<2048, 256, 0, stream>>>(features, proposals, task_p,
                                            task_y, task_wy, off, counter,
                                            rowbuf);
  finalize_kernel<<<N_IMG * R_PROP, 1024, 0, stream>>>(
      rowbuf, off, sblk, proposals, W_cls, W_box, b_cls, b_box, boxes_dec,
      scores);
  nms_kernel<<<N_IMG, 1024, 0, stream>>>(boxes_dec, scores, out_det);
}

// Round 3
// 199.447 us; speedup vs baseline: 1.2729x; 1.2729x over previous
//
#include <hip/hip_runtime.h>
#include <math.h>

// Problem constants (from reference)
#define N_IMG 2
#define R_PROP 256
#define G_GT 64
#define C_CH 1024
#define FH 50
#define FW 80
#define P_POOL 14
#define NCLS 80
#define IMG_W_F 1280.0f
#define IMG_H_F 800.0f
#define SCALE_F 0.0625f
#define SCORE_TH_F 0.05f
#define NMS_TH_F 0.5f
#define IOU_TH_F 0.5f
#define MAX_DET_I 100
#define SCALE_CLAMP_F 4.135166556742356f  // log(1000/16)

#define NQ 4                               // channel quarters per proposal
#define NTASK (N_IMG * R_PROP * NQ)        // 2048
#define QCH (C_CH / NQ)                    // 256 channels per task

// ---------------------------------------------------------------------------
// Kernel 1 (prep): LPT cost rank (descending window area) + gt matching +
// queue counter reset.
// ---------------------------------------------------------------------------
__global__ __launch_bounds__(512) void prep_kernel(
    const float* __restrict__ proposals,  // (N,R,4)
    const float* __restrict__ gt_boxes,   // (N,G,4)
    int* __restrict__ sq,                 // (512) LPT rank -> proposal id
    int* __restrict__ counter,            // queue counter
    float* __restrict__ out_idx,          // (N,R) as float
    float* __restrict__ out_lbl) {        // (N,R) as float
  const int t = threadIdx.x;      // 0..511  (global proposal id)
  const int n = t >> 8;
  __shared__ int s_cost[N_IMG * R_PROP];

  const float* pb = proposals + (size_t)t * 4;
  float bx1 = pb[0], by1 = pb[1], bx2 = pb[2], by2 = pb[3];
  if (t == 0) counter[0] = 0;

  // window cell count (same clamped-bounds arithmetic as roihead)
  {
    float b1y = by1 * SCALE_F, b2y = by2 * SCALE_F;
    float bsy = (b2y - b1y) * (1.0f / P_POOL);
    float gy0  = fminf(fmaxf(b1y + 0.5f  * bsy - 0.5f, 0.0f), (float)(FH - 1));
    float gy13 = fminf(fmaxf(b1y + 13.5f * bsy - 0.5f, 0.0f), (float)(FH - 1));
    int ylo = (int)floorf(gy0);
    int yhi = min((int)floorf(gy13) + 1, FH - 1);
    float b1x = bx1 * SCALE_F, b2x = bx2 * SCALE_F;
    float bsx = (b2x - b1x) * (1.0f / P_POOL);
    float gx0  = fminf(fmaxf(b1x + 0.5f  * bsx - 0.5f, 0.0f), (float)(FW - 1));
    float gx13 = fminf(fmaxf(b1x + 13.5f * bsx - 0.5f, 0.0f), (float)(FW - 1));
    int xlo = (int)floorf(gx0);
    int xhi = min((int)floorf(gx13) + 1, FW - 1);
    s_cost[t] = (yhi - ylo + 1) * (xhi - xlo + 1);
  }
  __syncthreads();

  // descending-cost rank (stable by index) -> LPT queue order
  {
    int myc = s_cost[t];
    int rk = 0;
#pragma unroll 8
    for (int j = 0; j < N_IMG * R_PROP; ++j) {
      int cj = s_cost[j];
      rk += (cj > myc) || (cj == myc && j < t);
    }
    sq[rk] = t;
  }

  // gt matching
  {
    float area_b = (bx2 - bx1) * (by2 - by1);
    float best = -1.0f;
    int bidx = 0;
    const float* gt = gt_boxes + (size_t)n * G_GT * 4;
#pragma unroll 4
    for (int g = 0; g < G_GT; ++g) {
      float gx1 = gt[g * 4 + 0], gy1 = gt[g * 4 + 1];
      float gx2 = gt[g * 4 + 2], gy2 = gt[g * 4 + 3];
      float area_a = (gx2 - gx1) * (gy2 - gy1);
      float ix1 = fmaxf(gx1, bx1), iy1 = fmaxf(gy1, by1);
      float ix2 = fminf(gx2, bx2), iy2 = fminf(gy2, by2);
      float iw = fmaxf(ix2 - ix1, 0.0f), ih = fmaxf(iy2 - iy1, 0.0f);
      float inter = iw * ih;
      float iou = inter / fmaxf(area_a + area_b - inter, 1e-9f);
      if (iou > best) { best = iou; bidx = g; }
    }
    out_idx[t] = (float)bidx;
    out_lbl[t] = (best >= IOU_TH_F) ? 1.0f : 0.0f;
  }
}

// ---------------------------------------------------------------------------
// Kernel 2 (roihead, persistent LPT queue): task = (proposal, channel
// quarter). 1024 blocks x 512 threads (8 waves, ~11 KB LDS -> 4 blocks/CU,
// all resident). Each block pulls tasks in descending-cost order; avg 2
// pulls/block. Body = proven round-0 ROI accumulate + partial GEMV.
// ---------------------------------------------------------------------------
__global__ __launch_bounds__(512) void roihead_kernel(
    const float* __restrict__ features,   // (N, FH, FW, C)
    const float* __restrict__ proposals,  // (N, R, 4)
    const int* __restrict__ sq,           // (512) LPT order
    const float* __restrict__ W_cls,      // (C, 81)
    const float* __restrict__ W_box,      // (C, 4)
    int* __restrict__ counter,
    float* __restrict__ part) {           // (512, NQ, 85) partial logits
  const int t = threadIdx.x;            // 0..511
  const int c4 = t & 63;                // float4 lane within quarter
  const int g = t >> 6;                 // 0..7 row group

  __shared__ float s_Wy[FH];
  __shared__ float s_Wx[FW];
  __shared__ int s_b[4];                // y_lo, y_hi, x_lo, x_hi
  __shared__ float4 s_red[7][64];
  __shared__ __align__(16) float sf[QCH];
  __shared__ float s_part[6][85];
  __shared__ int s_tid;

  for (;;) {
    __syncthreads();                    // previous iteration done with LDS
    if (t < FH) s_Wy[t] = 0.0f;
    if (t >= 128 && t < 128 + FW) s_Wx[t - 128] = 0.0f;
    if (t == 0) s_tid = atomicAdd(counter, 1);
    __syncthreads();
    const int tid = s_tid;
    if (tid >= NTASK) break;            // uniform exit

    const int p = sq[tid >> 2];         // proposal (LPT order)
    const int q = tid & 3;              // channel quarter
    const int qbase = q * QCH;
    const float* feat = features + (size_t)(p >> 8) * (FH * FW * C_CH) + qbase;

    if (t < 2 * P_POOL) {
      const float* pb = proposals + (size_t)p * 4;
      bool isY = t < P_POOL;
      int i = isY ? t : t - P_POOL;
      float lo = isY ? pb[1] : pb[0];
      float hi = isY ? pb[3] : pb[2];
      float limit = isY ? (float)(FH - 1) : (float)(FW - 1);
      float b1 = lo * SCALE_F, b2 = hi * SCALE_F;
      float bs = (b2 - b1) * (1.0f / P_POOL);
      float gg = b1 + ((float)i + 0.5f) * bs - 0.5f;
      gg = fminf(fmaxf(gg, 0.0f), limit);
      float fl = floorf(gg);
      int i0 = (int)fl;
      int i1 = min(i0 + 1, (int)limit);
      float l = gg - fl;
      if (isY) {
        atomicAdd(&s_Wy[i0], 1.0f - l);
        atomicAdd(&s_Wy[i1], l);
        if (i == 0) s_b[0] = i0;
        if (i == P_POOL - 1) s_b[1] = i1;
      } else {
        atomicAdd(&s_Wx[i0], 1.0f - l);
        atomicAdd(&s_Wx[i1], l);
        if (i == 0) s_b[2] = i0;
        if (i == P_POOL - 1) s_b[3] = i1;
      }
    }
    __syncthreads();

    // ---- ROI accumulate: 8-way row split over this 256-channel quarter ----
    {
      const int ylo = s_b[0], yhi = s_b[1], xlo = s_b[2], xhi = s_b[3];
      float4 acc = make_float4(0.f, 0.f, 0.f, 0.f);
      for (int y = ylo + g; y <= yhi; y += 8) {
        float wy = s_Wy[y];
        const float4* row = (const float4*)(feat + (size_t)y * (FW * C_CH)) + c4;
#pragma unroll 8
        for (int x = xlo; x <= xhi; ++x) {
          float w = wy * s_Wx[x];
          float4 f = row[x * (C_CH / 4)];
          acc.x += w * f.x;
          acc.y += w * f.y;
          acc.z += w * f.z;
          acc.w += w * f.w;
        }
      }
      if (g > 0) s_red[g - 1][c4] = acc;
      __syncthreads();
      if (g == 0) {
        const float inv = 1.0f / (float)(P_POOL * P_POOL);
#pragma unroll
        for (int r = 0; r < 7; ++r) {
          float4 a = s_red[r][c4];
          acc.x += a.x; acc.y += a.y; acc.z += a.z; acc.w += a.w;
        }
        ((float4*)sf)[c4] =
            make_float4(acc.x * inv, acc.y * inv, acc.z * inv, acc.w * inv);
      }
      __syncthreads();
    }

    // ---- partial GEMV over this quarter's K=256, 6-way split ----
    {
      const int kq = t / 85;        // 0..6 (t>=510 -> 6, inactive)
      const int j = t - kq * 85;
      if (kq < 6) {
        float acc = 0.0f;
        if (j < 81) {
          const float* __restrict__ w = W_cls + (size_t)qbase * 81 + j;
#pragma unroll 8
          for (int k = kq; k < QCH; k += 6) acc += sf[k] * w[k * 81];
        } else {
          const float* __restrict__ w = W_box + (size_t)qbase * 4 + (j - 81);
#pragma unroll 8
          for (int k = kq; k < QCH; k += 6) acc += sf[k] * w[k * 4];
        }
        s_part[kq][j] = acc;
      }
    }
    __syncthreads();

    if (t < 85) {
      float acc = 0.0f;
#pragma unroll
      for (int r = 0; r < 6; ++r) acc += s_part[r][t];
      part[((size_t)p * NQ + q) * 85 + t] = acc;
    }
  }
}

// ---------------------------------------------------------------------------
// Kernel 3 (finalize): one block per proposal, 128 threads. Assemble logits
// from the four quarters + bias, shuffle-softmax, box decode.
// ---------------------------------------------------------------------------
__global__ __launch_bounds__(128) void finalize_kernel(
    const float* __restrict__ part,       // (512, NQ, 85)
    const float* __restrict__ proposals,  // (N,R,4)
    const float* __restrict__ b_cls,      // (81)
    const float* __restrict__ b_box,      // (4)
    float* __restrict__ boxes_dec,        // (N*R, 4)
    float* __restrict__ scores) {         // (N*R)
  const int blk = blockIdx.x;   // 0..511 (proposal id)
  const int t = threadIdx.x;
  __shared__ float sl[85];
  __shared__ float s_red[8];

  const float* pp = part + (size_t)blk * (NQ * 85);
  if (t < 85) {
    float bias = (t < 81) ? b_cls[t] : b_box[t - 81];
    sl[t] = pp[t] + pp[85 + t] + pp[170 + t] + pp[255 + t] + bias;
  }
  __syncthreads();

  {
    float xm = (t < 81) ? sl[t] : -INFINITY;        // max over all 81
    float xf = (t < NCLS) ? sl[t] : -INFINITY;      // max over fg 80
#pragma unroll
    for (int off = 32; off; off >>= 1) {
      xm = fmaxf(xm, __shfl_down(xm, off, 64));
      xf = fmaxf(xf, __shfl_down(xf, off, 64));
    }
    if ((t & 63) == 0) { s_red[t >> 6] = xm; s_red[2 + (t >> 6)] = xf; }
  }
  __syncthreads();
  const float m = fmaxf(s_red[0], s_red[1]);
  {
    float xs = (t < 81) ? expf(sl[t] - m) : 0.0f;
#pragma unroll
    for (int off = 32; off; off >>= 1) xs += __shfl_down(xs, off, 64);
    if ((t & 63) == 0) s_red[4 + (t >> 6)] = xs;
  }
  __syncthreads();

  if (t == 0) {
    float sum = s_red[4] + s_red[5];
    float fgm = fmaxf(s_red[2], s_red[3]);
    scores[blk] = expf(fgm - m) / sum;

    const float* pb = proposals + (size_t)blk * 4;
    float w = pb[2] - pb[0], h = pb[3] - pb[1];
    float cx = pb[0] + 0.5f * w, cy = pb[1] + 0.5f * h;
    float dx = sl[81] * 0.1f;
    float dy = sl[82] * 0.1f;
    float dw = fminf(sl[83] * 0.2f, SCALE_CLAMP_F);
    float dh = fminf(sl[84] * 0.2f, SCALE_CLAMP_F);
    float pcx = dx * w + cx, pcy = dy * h + cy;
    float pw = expf(dw) * w, ph = expf(dh) * h;
    float ox1 = fminf(fmaxf(pcx - 0.5f * pw, 0.0f), IMG_W_F);
    float oy1 = fminf(fmaxf(pcy - 0.5f * ph, 0.0f), IMG_H_F);
    float ox2 = fminf(fmaxf(pcx + 0.5f * pw, 0.0f), IMG_W_F);
    float oy2 = fminf(fmaxf(pcy + 0.5f * ph, 0.0f), IMG_H_F);
    float* bd = boxes_dec + (size_t)blk * 4;
    bd[0] = ox1; bd[1] = oy1; bd[2] = ox2; bd[3] = oy2;
  }
}

// ---------------------------------------------------------------------------
// Kernel 4: greedy NMS + score filter + top-100 rank + det write (LDS-only
// after the initial 256 box/score loads).
// ---------------------------------------------------------------------------
__global__ __launch_bounds__(1024) void nms_kernel(
    const float* __restrict__ boxes_dec,  // (N*R, 4)
    const float* __restrict__ scores,     // (N*R)
    float* __restrict__ det) {            // (N, R, 6)
  const int n = blockIdx.x;
  const int u = threadIdx.x;
  const int i = u & 255;
  const int q = u >> 8;           // 0..3
  const int j40 = q * 16;         // float4 index start for this quarter

  __shared__ __align__(16) float ss[R_PROP];     // scores, original order
  __shared__ float4 sbs[R_PROP];                 // sorted boxes
  __shared__ int s_part[4 * R_PROP];             // partial rank counts
  __shared__ int s_rank[R_PROP];
  __shared__ __align__(16) unsigned long long s_mask[R_PROP * 4];
  __shared__ unsigned long long s_keep[4];
  __shared__ __align__(16) float sm[R_PROP];     // masked scores, orig order

  float4 myb;
  float mys;
  if (q == 0) {
    myb = ((const float4*)boxes_dec)[n * R_PROP + i];
    mys = scores[n * R_PROP + i];
    ss[i] = mys;
  }
  __syncthreads();

  // stable descending rank (ties by original index): float4 loads, 16/thread
  {
    float s = ss[i];
    int cnt = 0;
#pragma unroll
    for (int j4 = j40; j4 < j40 + 16; ++j4) {
      float4 v = ((const float4*)ss)[j4];
      int jb = j4 * 4;
      cnt += (v.x > s) || (v.x == s && jb + 0 < i);
      cnt += (v.y > s) || (v.y == s && jb + 1 < i);
      cnt += (v.z > s) || (v.z == s && jb + 2 < i);
      cnt += (v.w > s) || (v.w == s && jb + 3 < i);
    }
    s_part[q * R_PROP + i] = cnt;
  }
  __syncthreads();
  if (q == 0) {
    int rk = s_part[i] + s_part[R_PROP + i] + s_part[2 * R_PROP + i] +
             s_part[3 * R_PROP + i];
    s_rank[i] = rk;
    sbs[rk] = myb;
  }
  __syncthreads();

  // phase 1: thread (i,q) computes mask word q of sorted box i vs sorted j
  {
    float4 bi = sbs[i];
    float area_i = (bi.z - bi.x) * (bi.w - bi.y);
    unsigned long long m = 0;
    const int j0 = q * 64;
#pragma unroll 8
    for (int jj = 0; jj < 64; ++jj) {
      float4 bj = sbs[j0 + jj];
      float area_j = (bj.z - bj.x) * (bj.w - bj.y);
      float ix1 = fmaxf(bi.x, bj.x), iy1 = fmaxf(bi.y, bj.y);
      float ix2 = fminf(bi.z, bj.z), iy2 = fminf(bi.w, bj.w);
      float iw = fmaxf(ix2 - ix1, 0.0f), ih = fmaxf(iy2 - iy1, 0.0f);
      float inter = iw * ih;
      float iou = inter / fmaxf(area_i + area_j - inter, 1e-9f);
      m |= (iou > NMS_TH_F) ? (1ull << jj) : 0ull;
    }
    s_mask[i * 4 + q] = m;
  }
  __syncthreads();

  // phase 2: branchless serial greedy pass over sorted order (thread 0).
  if (u == 0) {
    unsigned long long K0 = ~0ull, K1 = ~0ull, K2 = ~0ull, K3 = ~0ull;
#pragma unroll 16
    for (int b = 1; b < 64; ++b) {
      unsigned long long m0 = s_mask[(size_t)b * 4 + 0];
      unsigned long long sup = m0 & K0 & ((1ull << b) - 1ull);
      K0 = sup ? (K0 & ~(1ull << b)) : K0;
    }
#pragma unroll 16
    for (int b = 0; b < 64; ++b) {
      const unsigned long long* mi = &s_mask[(size_t)(64 + b) * 4];
      unsigned long long m0 = mi[0], m1 = mi[1];
      unsigned long long sup = (m0 & K0) | (m1 & K1 & ((1ull << b) - 1ull));
      K1 = sup ? (K1 & ~(1ull << b)) : K1;
    }
#pragma unroll 16
    for (int b = 0; b < 64; ++b) {
      const unsigned long long* mi = &s_mask[(size_t)(128 + b) * 4];
      unsigned long long m0 = mi[0], m1 = mi[1], m2 = mi[2];
      unsigned long long sup =
          (m0 & K0) | (m1 & K1) | (m2 & K2 & ((1ull << b) - 1ull));
      K2 = sup ? (K2 & ~(1ull << b)) : K2;
    }
#pragma unroll 16
    for (int b = 0; b < 64; ++b) {
      const unsigned long long* mi = &s_mask[(size_t)(192 + b) * 4];
      unsigned long long m0 = mi[0], m1 = mi[1], m2 = mi[2], m3 = mi[3];
      unsigned long long sup = (m0 & K0) | (m1 & K1) | (m2 & K2) |
                               (m3 & K3 & ((1ull << b) - 1ull));
      K3 = sup ? (K3 & ~(1ull << b)) : K3;
    }
    s_keep[0] = K0; s_keep[1] = K1; s_keep[2] = K2; s_keep[3] = K3;
  }
  __syncthreads();

  bool kept = false;
  if (q == 0) {
    int rk = s_rank[i];
    kept = ((s_keep[rk >> 6] >> (rk & 63)) & 1ull) && (mys > SCORE_TH_F);
    sm[i] = kept ? mys : -INFINITY;
  }
  __syncthreads();

  // top-100 rank over masked scores: float4 loads, 16/thread
  {
    float mym = sm[i];
    int cnt = 0;
#pragma unroll
    for (int j4 = j40; j4 < j40 + 16; ++j4) {
      float4 v = ((const float4*)sm)[j4];
      int jb = j4 * 4;
      cnt += (v.x > mym) || (v.x == mym && jb + 0 < i);
      cnt += (v.y > mym) || (v.y == mym && jb + 1 < i);
      cnt += (v.z > mym) || (v.z == mym && jb + 2 < i);
      cnt += (v.w > mym) || (v.w == mym && jb + 3 < i);
    }
    s_part[q * R_PROP + i] = cnt;
  }
  __syncthreads();

  if (q == 0) {
    int rk2 = s_part[i] + s_part[R_PROP + i] + s_part[2 * R_PROP + i] +
              s_part[3 * R_PROP + i];
    kept = kept && (rk2 < MAX_DET_I);
    float* dr = det + ((size_t)n * R_PROP + i) * 6;
    dr[0] = myb.x; dr[1] = myb.y; dr[2] = myb.z; dr[3] = myb.w;
    dr[4] = mys;
    dr[5] = kept ? 1.0f : 0.0f;
  }
}

// ---------------------------------------------------------------------------
extern "C" void kernel_launch(void* const* d_in, const int* in_sizes, int n_in,
                              void* d_out, int out_size, void* d_ws, size_t ws_size,
                              hipStream_t stream) {
  const float* features  = (const float*)d_in[0];  // (2,50,80,1024)
  const float* proposals = (const float*)d_in[1];  // (2,256,4)
  const float* gt_boxes  = (const float*)d_in[2];  // (2,64,4)
  // d_in[3] gt_classes: unused by reference outputs
  const float* W_cls = (const float*)d_in[4];      // (1024,81)
  const float* b_cls = (const float*)d_in[5];      // (81)
  const float* W_box = (const float*)d_in[6];      // (1024,4)
  const float* b_box = (const float*)d_in[7];      // (4)

  float* out = (float*)d_out;
  // out layout: det [0,3072) | matched_idxs [3072,3584) | match_labels [3584,4096)
  float* out_det = out;
  float* out_idx = out + N_IMG * R_PROP * 6;
  float* out_lbl = out_idx + N_IMG * R_PROP;

  // workspace layout
  int*   counter   = (int*)d_ws;                        // [0]
  int*   sq        = counter + 16;                      // 512 ints
  float* part      = (float*)(sq + 512);                // 512*NQ*85
  float* boxes_dec = part + (size_t)N_IMG * R_PROP * NQ * 85;
  float* scores    = boxes_dec + (size_t)N_IMG * R_PROP * 4;

  prep_kernel<<<1, 512, 0, stream>>>(proposals, gt_boxes, sq, counter,
                                     out_idx, out_lbl);
  roihead_kernel<<<1024, 512, 0, stream>>>(features, proposals, sq, W_cls,
                                           W_box, counter, part);
  finalize_kernel<<<N_IMG * R_PROP, 128, 0, stream>>>(
      part, proposals, b_cls, b_box, boxes_dec, scores);
  nms_kernel<<<N_IMG, 1024, 0, stream>>>(boxes_dec, scores, out_det);
}

// Round 4
// 163.737 us; speedup vs baseline: 1.5505x; 1.2181x over previous
//
#include <hip/hip_runtime.h>
#include <math.h>

// Problem constants (from reference)
#define N_IMG 2
#define R_PROP 256
#define G_GT 64
#define C_CH 1024
#define FH 50
#define FW 80
#define P_POOL 14
#define NCLS 80
#define IMG_W_F 1280.0f
#define IMG_H_F 800.0f
#define SCALE_F 0.0625f
#define SCORE_TH_F 0.05f
#define NMS_TH_F 0.5f
#define IOU_TH_F 0.5f
#define MAX_DET_I 100
#define SCALE_CLAMP_F 4.135166556742356f  // log(1000/16)

#define NQ 4                               // channel quarters per proposal
#define QCH (C_CH / NQ)                    // 256 channels per task

// ---------------------------------------------------------------------------
// Kernel 1 (prep): y-center sort (perm for XCD banding) + gt matching.
// (round-1's proven prep, no queue counter)
// ---------------------------------------------------------------------------
__global__ __launch_bounds__(512) void prep_kernel(
    const float* __restrict__ proposals,  // (N,R,4)
    const float* __restrict__ gt_boxes,   // (N,G,4)
    int* __restrict__ perm,               // (N*R) y-sorted order
    float* __restrict__ out_idx,          // (N,R) as float
    float* __restrict__ out_lbl) {        // (N,R) as float
  const int t = threadIdx.x;      // 0..511
  const int n = t >> 8;
  __shared__ float cy[N_IMG * R_PROP];
  const float* pb = proposals + (size_t)t * 4;
  float bx1 = pb[0], by1 = pb[1], bx2 = pb[2], by2 = pb[3];
  cy[t] = by1 + by2;              // 2*cy, monotone in cy
  __syncthreads();

  // y-rank within image
  {
    float my = cy[t];
    int rk = 0;
    const int base = n * R_PROP;
#pragma unroll 8
    for (int j = base; j < base + R_PROP; ++j) {
      float cj = cy[j];
      rk += (cj < my) || (cj == my && j < t);
    }
    perm[base + rk] = t & 255;
  }

  // gt matching
  {
    float area_b = (bx2 - bx1) * (by2 - by1);
    float best = -1.0f;
    int bidx = 0;
    const float* gt = gt_boxes + (size_t)n * G_GT * 4;
#pragma unroll 4
    for (int g = 0; g < G_GT; ++g) {
      float gx1 = gt[g * 4 + 0], gy1 = gt[g * 4 + 1];
      float gx2 = gt[g * 4 + 2], gy2 = gt[g * 4 + 3];
      float area_a = (gx2 - gx1) * (gy2 - gy1);
      float ix1 = fmaxf(gx1, bx1), iy1 = fmaxf(gy1, by1);
      float ix2 = fminf(gx2, bx2), iy2 = fminf(gy2, by2);
      float iw = fmaxf(ix2 - ix1, 0.0f), ih = fmaxf(iy2 - iy1, 0.0f);
      float inter = iw * ih;
      float iou = inter / fmaxf(area_a + area_b - inter, 1e-9f);
      if (iou > best) { best = iou; bidx = g; }
    }
    out_idx[t] = (float)bidx;
    out_lbl[t] = (best >= IOU_TH_F) ? 1.0f : 0.0f;
  }
}

// ---------------------------------------------------------------------------
// Kernel 2 (roihead): STATIC fine-grained tiles. 2048 blocks x 256 threads
// (4 waves, ~6 KB LDS -> ~8 blocks/CU -> ~8 dispatch rounds for HW-level
// rebalancing). Task = (proposal, channel quarter). XCD banding + y-sort
// preserved: b&7 selects (image, y-band); consecutive b share a proposal's
// quarters on the same XCD. Writes part[p][q][85] partial logits (no bias).
// ---------------------------------------------------------------------------
__global__ __launch_bounds__(256) void roihead_kernel(
    const float* __restrict__ features,   // (N, FH, FW, C)
    const float* __restrict__ proposals,  // (N, R, 4)
    const int* __restrict__ perm,         // (N*R) y-sorted order
    const float* __restrict__ W_cls,      // (C, 81)
    const float* __restrict__ W_box,      // (C, 4)
    float* __restrict__ part) {           // (512, NQ, 85)
  const int b = blockIdx.x;             // 0..2047
  const int xcd = b & 7;
  const int slot = b >> 3;              // 0..255
  const int n = xcd >> 2;               // image
  const int band = xcd & 3;
  const int q = slot & 3;               // channel quarter
  const int p = n * R_PROP + perm[n * R_PROP + band * 64 + (slot >> 2)];
  const int qbase = q * QCH;

  const float* feat = features + (size_t)n * (FH * FW * C_CH) + qbase;
  const int t = threadIdx.x;
  const int c4 = t & 63;                // float4 lane within quarter (0..63)
  const int g = t >> 6;                 // 0..3 row group

  __shared__ float s_Wy[FH];
  __shared__ float s_Wx[FW];
  __shared__ int s_b[4];                // y_lo, y_hi, x_lo, x_hi
  __shared__ float4 s_red[3][64];
  __shared__ __align__(16) float sf[QCH];
  __shared__ float s_part[3][85];

  if (t < FH) s_Wy[t] = 0.0f;
  if (t >= 128 && t < 128 + FW) s_Wx[t - 128] = 0.0f;
  __syncthreads();

  if (t < 2 * P_POOL) {
    const float* pb = proposals + (size_t)p * 4;
    bool isY = t < P_POOL;
    int i = isY ? t : t - P_POOL;
    float lo = isY ? pb[1] : pb[0];
    float hi = isY ? pb[3] : pb[2];
    float limit = isY ? (float)(FH - 1) : (float)(FW - 1);
    float b1 = lo * SCALE_F, b2 = hi * SCALE_F;
    float bs = (b2 - b1) * (1.0f / P_POOL);
    float gg = b1 + ((float)i + 0.5f) * bs - 0.5f;
    gg = fminf(fmaxf(gg, 0.0f), limit);
    float fl = floorf(gg);
    int i0 = (int)fl;
    int i1 = min(i0 + 1, (int)limit);
    float l = gg - fl;
    if (isY) {
      atomicAdd(&s_Wy[i0], 1.0f - l);
      atomicAdd(&s_Wy[i1], l);
      if (i == 0) s_b[0] = i0;
      if (i == P_POOL - 1) s_b[1] = i1;
    } else {
      atomicAdd(&s_Wx[i0], 1.0f - l);
      atomicAdd(&s_Wx[i1], l);
      if (i == 0) s_b[2] = i0;
      if (i == P_POOL - 1) s_b[3] = i1;
    }
  }
  __syncthreads();

  // ---- phase 1: ROI accumulate, 4-way row split over this 256-ch quarter ----
  {
    const int ylo = s_b[0], yhi = s_b[1], xlo = s_b[2], xhi = s_b[3];
    float4 acc = make_float4(0.f, 0.f, 0.f, 0.f);
    for (int y = ylo + g; y <= yhi; y += 4) {
      float wy = s_Wy[y];
      const float4* row = (const float4*)(feat + (size_t)y * (FW * C_CH)) + c4;
#pragma unroll 8
      for (int x = xlo; x <= xhi; ++x) {
        float w = wy * s_Wx[x];
        float4 f = row[x * (C_CH / 4)];
        acc.x += w * f.x;
        acc.y += w * f.y;
        acc.z += w * f.z;
        acc.w += w * f.w;
      }
    }
    if (g > 0) s_red[g - 1][c4] = acc;
    __syncthreads();
    if (g == 0) {
      const float inv = 1.0f / (float)(P_POOL * P_POOL);
#pragma unroll
      for (int r = 0; r < 3; ++r) {
        float4 a = s_red[r][c4];
        acc.x += a.x; acc.y += a.y; acc.z += a.z; acc.w += a.w;
      }
      ((float4*)sf)[c4] =
          make_float4(acc.x * inv, acc.y * inv, acc.z * inv, acc.w * inv);
    }
    __syncthreads();
  }

  // ---- phase 2: partial GEMV over this quarter's K=256, 3-way split ----
  {
    const int kq = t / 85;        // 0..3 (t=255 -> 3, inactive)
    const int j = t - kq * 85;
    if (kq < 3) {
      float acc = 0.0f;
      if (j < 81) {
        const float* __restrict__ w = W_cls + (size_t)qbase * 81 + j;
#pragma unroll 8
        for (int k = kq; k < QCH; k += 3) acc += sf[k] * w[k * 81];
      } else {
        const float* __restrict__ w = W_box + (size_t)qbase * 4 + (j - 81);
#pragma unroll 8
        for (int k = kq; k < QCH; k += 3) acc += sf[k] * w[k * 4];
      }
      s_part[kq][j] = acc;
    }
  }
  __syncthreads();

  if (t < 85) {
    float acc = s_part[0][t] + s_part[1][t] + s_part[2][t];
    part[((size_t)p * NQ + q) * 85 + t] = acc;
  }
}

// ---------------------------------------------------------------------------
// Kernel 3 (finalize): one block per proposal, 128 threads. Assemble logits
// from the four quarters + bias, shuffle-softmax, box decode.
// ---------------------------------------------------------------------------
__global__ __launch_bounds__(128) void finalize_kernel(
    const float* __restrict__ part,       // (512, NQ, 85)
    const float* __restrict__ proposals,  // (N,R,4)
    const float* __restrict__ b_cls,      // (81)
    const float* __restrict__ b_box,      // (4)
    float* __restrict__ boxes_dec,        // (N*R, 4)
    float* __restrict__ scores) {         // (N*R)
  const int blk = blockIdx.x;   // 0..511 (proposal id)
  const int t = threadIdx.x;
  __shared__ float sl[85];
  __shared__ float s_red[8];

  const float* pp = part + (size_t)blk * (NQ * 85);
  if (t < 85) {
    float bias = (t < 81) ? b_cls[t] : b_box[t - 81];
    sl[t] = pp[t] + pp[85 + t] + pp[170 + t] + pp[255 + t] + bias;
  }
  __syncthreads();

  {
    float xm = (t < 81) ? sl[t] : -INFINITY;        // max over all 81
    float xf = (t < NCLS) ? sl[t] : -INFINITY;      // max over fg 80
#pragma unroll
    for (int off = 32; off; off >>= 1) {
      xm = fmaxf(xm, __shfl_down(xm, off, 64));
      xf = fmaxf(xf, __shfl_down(xf, off, 64));
    }
    if ((t & 63) == 0) { s_red[t >> 6] = xm; s_red[2 + (t >> 6)] = xf; }
  }
  __syncthreads();
  const float m = fmaxf(s_red[0], s_red[1]);
  {
    float xs = (t < 81) ? expf(sl[t] - m) : 0.0f;
#pragma unroll
    for (int off = 32; off; off >>= 1) xs += __shfl_down(xs, off, 64);
    if ((t & 63) == 0) s_red[4 + (t >> 6)] = xs;
  }
  __syncthreads();

  if (t == 0) {
    float sum = s_red[4] + s_red[5];
    float fgm = fmaxf(s_red[2], s_red[3]);
    scores[blk] = expf(fgm - m) / sum;

    const float* pb = proposals + (size_t)blk * 4;
    float w = pb[2] - pb[0], h = pb[3] - pb[1];
    float cx = pb[0] + 0.5f * w, cy = pb[1] + 0.5f * h;
    float dx = sl[81] * 0.1f;
    float dy = sl[82] * 0.1f;
    float dw = fminf(sl[83] * 0.2f, SCALE_CLAMP_F);
    float dh = fminf(sl[84] * 0.2f, SCALE_CLAMP_F);
    float pcx = dx * w + cx, pcy = dy * h + cy;
    float pw = expf(dw) * w, ph = expf(dh) * h;
    float ox1 = fminf(fmaxf(pcx - 0.5f * pw, 0.0f), IMG_W_F);
    float oy1 = fminf(fmaxf(pcy - 0.5f * ph, 0.0f), IMG_H_F);
    float ox2 = fminf(fmaxf(pcx + 0.5f * pw, 0.0f), IMG_W_F);
    float oy2 = fminf(fmaxf(pcy + 0.5f * ph, 0.0f), IMG_H_F);
    float* bd = boxes_dec + (size_t)blk * 4;
    bd[0] = ox1; bd[1] = oy1; bd[2] = ox2; bd[3] = oy2;
  }
}

// ---------------------------------------------------------------------------
// Kernel 4: greedy NMS + score filter + top-100 rank + det write (LDS-only
// after the initial 256 box/score loads).
// ---------------------------------------------------------------------------
__global__ __launch_bounds__(1024) void nms_kernel(
    const float* __restrict__ boxes_dec,  // (N*R, 4)
    const float* __restrict__ scores,     // (N*R)
    float* __restrict__ det) {            // (N, R, 6)
  const int n = blockIdx.x;
  const int u = threadIdx.x;
  const int i = u & 255;
  const int q = u >> 8;           // 0..3
  const int j40 = q * 16;         // float4 index start for this quarter

  __shared__ __align__(16) float ss[R_PROP];     // scores, original order
  __shared__ float4 sbs[R_PROP];                 // sorted boxes
  __shared__ int s_part[4 * R_PROP];             // partial rank counts
  __shared__ int s_rank[R_PROP];
  __shared__ __align__(16) unsigned long long s_mask[R_PROP * 4];
  __shared__ unsigned long long s_keep[4];
  __shared__ __align__(16) float sm[R_PROP];     // masked scores, orig order

  float4 myb;
  float mys;
  if (q == 0) {
    myb = ((const float4*)boxes_dec)[n * R_PROP + i];
    mys = scores[n * R_PROP + i];
    ss[i] = mys;
  }
  __syncthreads();

  // stable descending rank (ties by original index): float4 loads, 16/thread
  {
    float s = ss[i];
    int cnt = 0;
#pragma unroll
    for (int j4 = j40; j4 < j40 + 16; ++j4) {
      float4 v = ((const float4*)ss)[j4];
      int jb = j4 * 4;
      cnt += (v.x > s) || (v.x == s && jb + 0 < i);
      cnt += (v.y > s) || (v.y == s && jb + 1 < i);
      cnt += (v.z > s) || (v.z == s && jb + 2 < i);
      cnt += (v.w > s) || (v.w == s && jb + 3 < i);
    }
    s_part[q * R_PROP + i] = cnt;
  }
  __syncthreads();
  if (q == 0) {
    int rk = s_part[i] + s_part[R_PROP + i] + s_part[2 * R_PROP + i] +
             s_part[3 * R_PROP + i];
    s_rank[i] = rk;
    sbs[rk] = myb;
  }
  __syncthreads();

  // phase 1: thread (i,q) computes mask word q of sorted box i vs sorted j
  {
    float4 bi = sbs[i];
    float area_i = (bi.z - bi.x) * (bi.w - bi.y);
    unsigned long long m = 0;
    const int j0 = q * 64;
#pragma unroll 8
    for (int jj = 0; jj < 64; ++jj) {
      float4 bj = sbs[j0 + jj];
      float area_j = (bj.z - bj.x) * (bj.w - bj.y);
      float ix1 = fmaxf(bi.x, bj.x), iy1 = fmaxf(bi.y, bj.y);
      float ix2 = fminf(bi.z, bj.z), iy2 = fminf(bi.w, bj.w);
      float iw = fmaxf(ix2 - ix1, 0.0f), ih = fmaxf(iy2 - iy1, 0.0f);
      float inter = iw * ih;
      float iou = inter / fmaxf(area_i + area_j - inter, 1e-9f);
      m |= (iou > NMS_TH_F) ? (1ull << jj) : 0ull;
    }
    s_mask[i * 4 + q] = m;
  }
  __syncthreads();

  // phase 2: branchless serial greedy pass over sorted order (thread 0).
  if (u == 0) {
    unsigned long long K0 = ~0ull, K1 = ~0ull, K2 = ~0ull, K3 = ~0ull;
#pragma unroll 16
    for (int b = 1; b < 64; ++b) {
      unsigned long long m0 = s_mask[(size_t)b * 4 + 0];
      unsigned long long sup = m0 & K0 & ((1ull << b) - 1ull);
      K0 = sup ? (K0 & ~(1ull << b)) : K0;
    }
#pragma unroll 16
    for (int b = 0; b < 64; ++b) {
      const unsigned long long* mi = &s_mask[(size_t)(64 + b) * 4];
      unsigned long long m0 = mi[0], m1 = mi[1];
      unsigned long long sup = (m0 & K0) | (m1 & K1 & ((1ull << b) - 1ull));
      K1 = sup ? (K1 & ~(1ull << b)) : K1;
    }
#pragma unroll 16
    for (int b = 0; b < 64; ++b) {
      const unsigned long long* mi = &s_mask[(size_t)(128 + b) * 4];
      unsigned long long m0 = mi[0], m1 = mi[1], m2 = mi[2];
      unsigned long long sup =
          (m0 & K0) | (m1 & K1) | (m2 & K2 & ((1ull << b) - 1ull));
      K2 = sup ? (K2 & ~(1ull << b)) : K2;
    }
#pragma unroll 16
    for (int b = 0; b < 64; ++b) {
      const unsigned long long* mi = &s_mask[(size_t)(192 + b) * 4];
      unsigned long long m0 = mi[0], m1 = mi[1], m2 = mi[2], m3 = mi[3];
      unsigned long long sup = (m0 & K0) | (m1 & K1) | (m2 & K2) |
                               (m3 & K3 & ((1ull << b) - 1ull));
      K3 = sup ? (K3 & ~(1ull << b)) : K3;
    }
    s_keep[0] = K0; s_keep[1] = K1; s_keep[2] = K2; s_keep[3] = K3;
  }
  __syncthreads();

  bool kept = false;
  if (q == 0) {
    int rk = s_rank[i];
    kept = ((s_keep[rk >> 6] >> (rk & 63)) & 1ull) && (mys > SCORE_TH_F);
    sm[i] = kept ? mys : -INFINITY;
  }
  __syncthreads();

  // top-100 rank over masked scores: float4 loads, 16/thread
  {
    float mym = sm[i];
    int cnt = 0;
#pragma unroll
    for (int j4 = j40; j4 < j40 + 16; ++j4) {
      float4 v = ((const float4*)sm)[j4];
      int jb = j4 * 4;
      cnt += (v.x > mym) || (v.x == mym && jb + 0 < i);
      cnt += (v.y > mym) || (v.y == mym && jb + 1 < i);
      cnt += (v.z > mym) || (v.z == mym && jb + 2 < i);
      cnt += (v.w > mym) || (v.w == mym && jb + 3 < i);
    }
    s_part[q * R_PROP + i] = cnt;
  }
  __syncthreads();

  if (q == 0) {
    int rk2 = s_part[i] + s_part[R_PROP + i] + s_part[2 * R_PROP + i] +
              s_part[3 * R_PROP + i];
    kept = kept && (rk2 < MAX_DET_I);
    float* dr = det + ((size_t)n * R_PROP + i) * 6;
    dr[0] = myb.x; dr[1] = myb.y; dr[2] = myb.z; dr[3] = myb.w;
    dr[4] = mys;
    dr[5] = kept ? 1.0f : 0.0f;
  }
}

// ---------------------------------------------------------------------------
extern "C" void kernel_launch(void* const* d_in, const int* in_sizes, int n_in,
                              void* d_out, int out_size, void* d_ws, size_t ws_size,
                              hipStream_t stream) {
  const float* features  = (const float*)d_in[0];  // (2,50,80,1024)
  const float* proposals = (const float*)d_in[1];  // (2,256,4)
  const float* gt_boxes  = (const float*)d_in[2];  // (2,64,4)
  // d_in[3] gt_classes: unused by reference outputs
  const float* W_cls = (const float*)d_in[4];      // (1024,81)
  const float* b_cls = (const float*)d_in[5];      // (81)
  const float* W_box = (const float*)d_in[6];      // (1024,4)
  const float* b_box = (const float*)d_in[7];      // (4)

  float* out = (float*)d_out;
  // out layout: det [0,3072) | matched_idxs [3072,3584) | match_labels [3584,4096)
  float* out_det = out;
  float* out_idx = out + N_IMG * R_PROP * 6;
  float* out_lbl = out_idx + N_IMG * R_PROP;

  // workspace layout
  int*   perm      = (int*)d_ws;                        // 512 ints
  float* part      = (float*)(perm + 512);              // 512*NQ*85
  float* boxes_dec = part + (size_t)N_IMG * R_PROP * NQ * 85;
  float* scores    = boxes_dec + (size_t)N_IMG * R_PROP * 4;

  prep_kernel<<<1, 512, 0, stream>>>(proposals, gt_boxes, perm, out_idx,
                                     out_lbl);
  roihead_kernel<<<N_IMG * R_PROP * NQ, 256, 0, stream>>>(
      features, proposals, perm, W_cls, W_box, part);
  finalize_kernel<<<N_IMG * R_PROP, 128, 0, stream>>>(
      part, proposals, b_cls, b_box, boxes_dec, scores);
  nms_kernel<<<N_IMG, 1024, 0, stream>>>(boxes_dec, scores, out_det);
}